// Round 1
// baseline (242.233 us; speedup 1.0000x reference)
//
#include <hip/hip_runtime.h>
#include <stdint.h>

#define N_NODES 20000
#define N_EDGES 320000
#define K_MIX 5
#define IN_F 256
#define OUT_F 128
#define NT 11              /* 1 + 2K column tiles of 128 */

typedef __attribute__((ext_vector_type(8))) short short8;
typedef __attribute__((ext_vector_type(4))) float floatx4;

__device__ __forceinline__ float bf2f(unsigned int u) {
  union { unsigned int i; float f; } v;
  v.i = (u & 0xffffu) << 16;
  return v.f;
}
__device__ __forceinline__ unsigned short f2bf(float f) {
  union { float f; unsigned int i; } v;
  v.f = f;
  unsigned int x = v.i;
  unsigned int r = (x + 0x7fffu + ((x >> 16) & 1u)) >> 16;
  return (unsigned short)r;
}

// E[relu(X)], X ~ N(mu, sig) (sig is variance). Fast erf: A&S 7.1.26 reusing
// exp(-w^2/2) (== exp(-x^2) for x = w/sqrt2). |erf err| < 1.5e-7.
__device__ __forceinline__ float exrelu(float mu, float sig) {
  if (sig < 1e-30f) return fmaxf(mu, 0.f);
  float ss = sqrtf(sig);
  float w = mu / ss;
  float e = __expf(-0.5f * w * w);
  float axv = fabsf(w) * 0.70710678118654752f;
  float t = 1.f / (1.f + 0.3275911f * axv);
  float poly = t * (0.254829592f +
              t * (-0.284496736f +
              t * (1.421413741f +
              t * (-1.453152027f + t * 1.061405429f))));
  float erfv = 1.f - poly * e;
  erfv = copysignf(erfv, w);
  return ss * (e * 0.3989422804014327f + 0.5f * w * (1.f + erfv));
}

// ---------------- degree ----------------
__global__ void k_deg(const int* __restrict__ row, int* __restrict__ deg) {
  int t = blockIdx.x * 256 + threadIdx.x;
  if (t < N_EDGES) atomicAdd(&deg[row[t]], 1);
}

// ---------------- CSR build: scan (+dinv fused) + scatter ----------------
__global__ void k_scan1(const int* __restrict__ deg, int* __restrict__ startofs,
                        int* __restrict__ bsums, float* __restrict__ dinv) {
  __shared__ int sd[256];
  int t = threadIdx.x;
  int i = blockIdx.x * 256 + t;
  int v = (i < N_NODES) ? deg[i] : 0;
  if (i < N_NODES) dinv[i] = rsqrtf((float)(v + 1));  // +1 self-loop
  sd[t] = v;
  __syncthreads();
  for (int off = 1; off < 256; off <<= 1) {
    int u = (t >= off) ? sd[t - off] : 0;
    __syncthreads();
    sd[t] += u;
    __syncthreads();
  }
  if (i < N_NODES) startofs[i] = sd[t] - v;
  if (t == 255) bsums[blockIdx.x] = sd[255];
}

__global__ void k_scan2(int* __restrict__ bsums, int nb) {
  __shared__ int sd[128];
  int t = threadIdx.x;
  int v = (t < nb) ? bsums[t] : 0;
  sd[t] = v;
  __syncthreads();
  for (int off = 1; off < 128; off <<= 1) {
    int u = (t >= off) ? sd[t - off] : 0;
    __syncthreads();
    sd[t] += u;
    __syncthreads();
  }
  if (t < nb) bsums[t] = sd[t] - v;  // exclusive
}

__global__ void k_scan3(int* __restrict__ startofs, int* __restrict__ cursor,
                        const int* __restrict__ bsums) {
  int i = blockIdx.x * 256 + threadIdx.x;
  if (i < N_NODES) {
    int s0 = startofs[i] + bsums[blockIdx.x];
    startofs[i] = s0;
    cursor[i] = s0;
  }
}

__global__ void k_scatter(const int* __restrict__ row, const int* __restrict__ col,
                          const float* __restrict__ dinv, int* __restrict__ cursor,
                          int* __restrict__ csr_col, float* __restrict__ csr_w) {
  int t = blockIdx.x * 256 + threadIdx.x;
  if (t < N_EDGES) {
    int r = row[t], c = col[t];
    int p = atomicAdd(&cursor[r], 1);
    csr_col[p] = c;
    csr_w[p] = dinv[r] * dinv[c];
  }
}

// ---------------- B-matrix build: Bt[j][n][k] bf16 (transposed for MFMA B) ----
__global__ void k_buildB(const float* __restrict__ W, const float* __restrict__ means,
                         const float* __restrict__ logvars, unsigned short* __restrict__ Bt) {
  int idx = blockIdx.x * 256 + threadIdx.x;  // < 11*128*256
  int j = idx >> 15;
  int rem = idx & 32767;
  int n = rem >> 8;
  int kk = rem & 255;
  float wv = W[kk * OUT_F + n];
  float val;
  if (j == 0) val = wv;                                        // W
  else if (j <= 5) val = means[(j - 1) * IN_F + kk] * wv;      // means_k * W
  else val = expf(logvars[(j - 6) * IN_F + kk]) * wv * wv;     // var_k * W^2
  Bt[idx] = f2bf(val);
}

// ---- prep: pack x -> bf16 X0 (NaN marker 0x7FC0 for missing) + gamma ---------
__global__ void k_prepx(const float* __restrict__ x, const float* __restrict__ logp,
                        const float* __restrict__ means, const float* __restrict__ logvars,
                        unsigned short* __restrict__ X0, float* __restrict__ gamma) {
  __shared__ float s_mean[K_MIX * IN_F];
  __shared__ float s_rv[K_MIX * IN_F];
  int t = threadIdx.x;
  for (int j = t; j < K_MIX * IN_F; j += 256) {
    s_mean[j] = means[j];
    s_rv[j] = expf(-logvars[j]);  // 1/var
  }
  __syncthreads();
  int node = blockIdx.x * 4 + (t >> 6);
  if (node >= N_NODES) return;
  int lane = t & 63;
  float4 xv = *(const float4*)(x + (size_t)node * IN_F + 4 * lane);
  float xf[4] = {xv.x, xv.y, xv.z, xv.w};
  float gsum[K_MIX] = {0, 0, 0, 0, 0};
  ushort4 o;
  unsigned short* op = (unsigned short*)&o;
#pragma unroll
  for (int j = 0; j < 4; j++) {
    bool nn = (xf[j] != xf[j]);
    op[j] = nn ? (unsigned short)0x7FC0 : f2bf(xf[j]);
    if (!nn) {
      int fi = 4 * lane + j;
#pragma unroll
      for (int k = 0; k < K_MIX; k++) {
        float d = xf[j] - s_mean[k * IN_F + fi];
        gsum[k] += d * d * s_rv[k * IN_F + fi];
      }
    }
  }
  *(ushort4*)(X0 + node * IN_F + 4 * lane) = o;
#pragma unroll
  for (int k = 0; k < K_MIX; k++)
    for (int off = 32; off; off >>= 1) gsum[k] += __shfl_xor(gsum[k], off, 64);
  if (lane == 0) {
    float lg[K_MIX], mx = -1e30f;
#pragma unroll
    for (int k = 0; k < K_MIX; k++) {
      lg[k] = logp[k] - 0.5f * gsum[k];
      mx = fmaxf(mx, lg[k]);
    }
    float se = 0.f;
#pragma unroll
    for (int k = 0; k < K_MIX; k++) { lg[k] = expf(lg[k] - mx); se += lg[k]; }
    float inv = 1.f / se;
#pragma unroll
    for (int k = 0; k < K_MIX; k++) gamma[node * K_MIX + k] = lg[k] * inv;
  }
}

// ---- fused 3-way SpMM: A@x0 | A@m | A2@m  (ONE 64-thread BLOCK per node) -----
// node = blockIdx.x is block-uniform -> compiler scalarizes CSR loads (s_load)
// and row-base address math; vector offset is loop-invariant. Depth-8 pipeline.
__global__ __launch_bounds__(64) void k_spmm(const unsigned short* __restrict__ X0,
                       const int* __restrict__ startofs, const int* __restrict__ deg,
                       const float* __restrict__ dinv, const int* __restrict__ csr_col,
                       const float* __restrict__ csr_w, unsigned short* __restrict__ G,
                       float* __restrict__ sArr) {
  int node = blockIdx.x;
  int lane = threadIdx.x;
  int fo = 4 * lane;
  float ax[4] = {0, 0, 0, 0}, am[4] = {0, 0, 0, 0}, am2[4] = {0, 0, 0, 0};
  float ssum = 0.f;
  float ws = dinv[node];
  ws = ws * ws;
  int st = startofs[node];
  int total = deg[node] + 1;  // virtual idx 0 = self loop, v>=1 -> edge v-1
  ushort4 zero4 = {0, 0, 0, 0};
  ushort4 B0 = zero4, B1 = zero4, B2 = zero4, B3 = zero4,
          B4 = zero4, B5 = zero4, B6 = zero4, B7 = zero4;
  float W0 = 0.f, W1 = 0.f, W2 = 0.f, W3 = 0.f,
        W4 = 0.f, W5 = 0.f, W6 = 0.f, W7 = 0.f;
  // prologue: fill slots with virtual idx 0..7
  B0 = *(const ushort4*)(X0 + node * IN_F + fo); W0 = ws;
#define PFILL(S)                                                      \
  if (S < total) {                                                    \
    int c = csr_col[st + (S - 1)];                                    \
    W##S = csr_w[st + (S - 1)];                                       \
    B##S = *(const ushort4*)(X0 + c * IN_F + fo);                     \
  }
  PFILL(1) PFILL(2) PFILL(3) PFILL(4) PFILL(5) PFILL(6) PFILL(7)
#undef PFILL

#define STEP(S)                                                       \
  if (W##S != 0.f) {                                                  \
    float wv = W##S, wv2 = wv * wv;                                   \
    ssum += wv;                                                       \
    const unsigned short* xp = (const unsigned short*)&B##S;          \
    _Pragma("unroll")                                                 \
    for (int j = 0; j < 4; j++) {                                     \
      float xf = bf2f(xp[j]);                                         \
      bool nn = (xf != xf);                                           \
      ax[j] = fmaf(wv, nn ? 0.f : xf, ax[j]);                         \
      am[j] += nn ? wv : 0.f;                                         \
      am2[j] += nn ? wv2 : 0.f;                                       \
    }                                                                 \
  }                                                                   \
  if (base + 8 + S < total) {                                         \
    int c = csr_col[st + base + 7 + S];                               \
    W##S = csr_w[st + base + 7 + S];                                  \
    B##S = *(const ushort4*)(X0 + c * IN_F + fo);                     \
  } else {                                                            \
    W##S = 0.f;                                                       \
  }

  for (int base = 0; base < total; base += 8) {
    STEP(0) STEP(1) STEP(2) STEP(3) STEP(4) STEP(5) STEP(6) STEP(7)
  }
#undef STEP

  ushort4 o;
  o.x = f2bf(ax[0]); o.y = f2bf(ax[1]); o.z = f2bf(ax[2]); o.w = f2bf(ax[3]);
  *(ushort4*)(G + node * 768 + fo) = o;
  o.x = f2bf(am[0]); o.y = f2bf(am[1]); o.z = f2bf(am[2]); o.w = f2bf(am[3]);
  *(ushort4*)(G + node * 768 + 256 + fo) = o;
  o.x = f2bf(am2[0]); o.y = f2bf(am2[1]); o.z = f2bf(am2[2]); o.w = f2bf(am2[3]);
  *(ushort4*)(G + node * 768 + 512 + fo) = o;
  if (lane == 0) sArr[node] = ssum;
}

// ---- fused MFMA GEMM + epilogue: out = sum_k gamma_k * ExRelu(cx+tm_k+b*s, tv_k)
// Block = 64 rows x 64 out-cols, grid (ceil(N/64), 2). All 11 jt tiles computed
// in-block so T is never materialized. LDS: A1+A2 full-K tiles (64KB) + 2 B
// chunk buffers (16KB) = 80KB -> 2 blocks/CU. Swizzle identical to the old
// verified k_gemm (16B chunk index XOR low-3 row bits).
__global__ __launch_bounds__(256, 2) void k_gemm_ep(
    const unsigned short* __restrict__ G, const unsigned short* __restrict__ Bt,
    const float* __restrict__ gamma, const float* __restrict__ sArr,
    const float* __restrict__ bias, float* __restrict__ out) {
  __shared__ __align__(16) char A1ls[64 * 512];  // 32 KB, rows x 256K bf16
  __shared__ __align__(16) char A2ls[64 * 512];  // 32 KB
  __shared__ __align__(16) char Bls0[64 * 128];  // 8 KB, 64 cols x 64K chunk
  __shared__ __align__(16) char Bls1[64 * 128];  // 8 KB
  int mt = blockIdx.x, ch = blockIdx.y;
  int t = threadIdx.x, wave = t >> 6, lane = t & 63;
  int wr = wave >> 1, wc = wave & 1;
  int quad = lane >> 4, l16 = lane & 15;

  floatx4 z = {0.f, 0.f, 0.f, 0.f};
  floatx4 cx[2][2], oa[2][2];
#pragma unroll
  for (int mi = 0; mi < 2; mi++)
#pragma unroll
    for (int ni = 0; ni < 2; ni++) { cx[mi][ni] = z; oa[mi][ni] = z; }

#define STAGE_A(dst, aoff_)                                              \
  {                                                                      \
    _Pragma("unroll")                                                    \
    for (int i = 0; i < 8; i++) {                                        \
      int f = i * 256 + t;                                               \
      int r = f >> 5, c = f & 31;                                        \
      int sw = c ^ (r & 7);                                              \
      int gr = mt * 64 + r;                                              \
      if (gr >= N_NODES) gr = N_NODES - 1;                               \
      *(uint4*)((dst) + r * 512 + sw * 16) =                             \
          *(const uint4*)(G + (size_t)gr * 768 + (aoff_) + c * 8);       \
    }                                                                    \
  }

#define STAGE_B(dst, jt_, k0_)                                           \
  {                                                                      \
    _Pragma("unroll")                                                    \
    for (int i = 0; i < 2; i++) {                                        \
      int f = i * 256 + t;                                               \
      int r = f >> 3, c = f & 7;                                         \
      int sw = c ^ (r & 7);                                              \
      *(uint4*)((dst) + r * 128 + sw * 16) =                             \
          *(const uint4*)(Bt + (size_t)(jt_)*32768 +                     \
                          (ch * 64 + r) * 256 + (k0_) + c * 8);          \
    }                                                                    \
  }

  // ---- phase 1: cx = (A@x0 slice) @ W, kept in f32 registers ----
  STAGE_A(A1ls, 0)
  for (int k0 = 0; k0 < 256; k0 += 64) {
    __syncthreads();
    STAGE_B(Bls0, 0, k0)
    __syncthreads();
#pragma unroll
    for (int ks = 0; ks < 2; ks++) {
      int ccA = (k0 >> 3) + ks * 4 + quad;
      int ccB = ks * 4 + quad;
      short8 a[2], b[2];
#pragma unroll
      for (int mi = 0; mi < 2; mi++) {
        int r = wr * 32 + mi * 16 + l16;
        a[mi] = *(const short8*)(A1ls + r * 512 + (ccA ^ (r & 7)) * 16);
      }
#pragma unroll
      for (int ni = 0; ni < 2; ni++) {
        int r = wc * 32 + ni * 16 + l16;
        b[ni] = *(const short8*)(Bls0 + r * 128 + (ccB ^ (r & 7)) * 16);
      }
#pragma unroll
      for (int mi = 0; mi < 2; mi++)
#pragma unroll
        for (int ni = 0; ni < 2; ni++)
          cx[mi][ni] = __builtin_amdgcn_mfma_f32_16x16x32_bf16(a[mi], b[ni], cx[mi][ni], 0, 0, 0);
    }
  }

  // ---- stage A1 (A@mask) and A2 (A2@mask) full-K tiles ----
  __syncthreads();   // protect A1ls (phase-1 reads) before overwrite
  STAGE_A(A1ls, 256)
  STAGE_A(A2ls, 512)

  // per-thread row/col metadata
  int gr0 = mt * 64 + wr * 32 + quad * 4;
  int gc0 = ch * 64 + wc * 32 + l16;
  float svr[2][4];
#pragma unroll
  for (int mi = 0; mi < 2; mi++)
#pragma unroll
    for (int reg = 0; reg < 4; reg++) {
      int gr = gr0 + mi * 16 + reg;
      if (gr >= N_NODES) gr = N_NODES - 1;
      svr[mi][reg] = sArr[gr];
    }
  float biasr[2] = {bias[gc0], bias[gc0 + 16]};

#pragma unroll 1
  for (int k = 0; k < K_MIX; k++) {
    floatx4 tm[2][2], tv[2][2];
#pragma unroll
    for (int mi = 0; mi < 2; mi++)
#pragma unroll
      for (int ni = 0; ni < 2; ni++) { tm[mi][ni] = z; tv[mi][ni] = z; }
    for (int k0 = 0; k0 < 256; k0 += 64) {
      __syncthreads();
      STAGE_B(Bls0, 1 + k, k0)
      STAGE_B(Bls1, 6 + k, k0)
      __syncthreads();
#pragma unroll
      for (int ks = 0; ks < 2; ks++) {
        int ccA = (k0 >> 3) + ks * 4 + quad;
        int ccB = ks * 4 + quad;
        short8 a1[2], a2[2], bm[2], bv[2];
#pragma unroll
        for (int mi = 0; mi < 2; mi++) {
          int r = wr * 32 + mi * 16 + l16;
          int sa = r * 512 + (ccA ^ (r & 7)) * 16;
          a1[mi] = *(const short8*)(A1ls + sa);
          a2[mi] = *(const short8*)(A2ls + sa);
        }
#pragma unroll
        for (int ni = 0; ni < 2; ni++) {
          int r = wc * 32 + ni * 16 + l16;
          int sb = r * 128 + (ccB ^ (r & 7)) * 16;
          bm[ni] = *(const short8*)(Bls0 + sb);
          bv[ni] = *(const short8*)(Bls1 + sb);
        }
#pragma unroll
        for (int mi = 0; mi < 2; mi++)
#pragma unroll
          for (int ni = 0; ni < 2; ni++) {
            tm[mi][ni] = __builtin_amdgcn_mfma_f32_16x16x32_bf16(a1[mi], bm[ni], tm[mi][ni], 0, 0, 0);
            tv[mi][ni] = __builtin_amdgcn_mfma_f32_16x16x32_bf16(a2[mi], bv[ni], tv[mi][ni], 0, 0, 0);
          }
      }
    }
    // epilogue for mixture component k: fold into output accumulator
#pragma unroll
    for (int mi = 0; mi < 2; mi++)
#pragma unroll
      for (int reg = 0; reg < 4; reg++) {
        int gr = gr0 + mi * 16 + reg;
        if (gr >= N_NODES) gr = N_NODES - 1;
        float g = gamma[gr * K_MIX + k];
#pragma unroll
        for (int ni = 0; ni < 2; ni++) {
          float mu = cx[mi][ni][reg] + tm[mi][ni][reg] + biasr[ni] * svr[mi][reg];
          oa[mi][ni][reg] += g * exrelu(mu, tv[mi][ni][reg]);
        }
      }
  }

  // store final f32 output
#pragma unroll
  for (int mi = 0; mi < 2; mi++)
#pragma unroll
    for (int ni = 0; ni < 2; ni++)
#pragma unroll
      for (int reg = 0; reg < 4; reg++) {
        int gr = gr0 + mi * 16 + reg;
        if (gr < N_NODES) out[(size_t)gr * OUT_F + gc0 + ni * 16] = oa[mi][ni][reg];
      }
#undef STAGE_A
#undef STAGE_B
}

extern "C" void kernel_launch(void* const* d_in, const int* in_sizes, int n_in,
                              void* d_out, int out_size, void* d_ws, size_t ws_size,
                              hipStream_t stream) {
  const float* x = (const float*)d_in[0];
  const int* ei = (const int*)d_in[1];
  const float* logp = (const float*)d_in[2];
  const float* means = (const float*)d_in[3];
  const float* lvar = (const float*)d_in[4];
  const float* W = (const float*)d_in[5];
  const float* bias = (const float*)d_in[6];
  float* out = (float*)d_out;
  const int* row = ei;
  const int* col = ei + N_EDGES;

  char* p = (char*)d_ws;
  auto alloc = [&](size_t bytes) -> char* {
    char* q = p;
    p += (bytes + 255) & ~((size_t)255);
    return q;
  };
  int* deg = (int*)alloc(N_NODES * 4);
  float* dinv = (float*)alloc(N_NODES * 4);
  int* startofs = (int*)alloc(N_NODES * 4);
  int* cursor = (int*)alloc(N_NODES * 4);
  int* bsums = (int*)alloc(128 * 4);
  int* csr_col = (int*)alloc((size_t)N_EDGES * 4);
  float* csr_w = (float*)alloc((size_t)N_EDGES * 4);
  float* gamma = (float*)alloc((size_t)N_NODES * K_MIX * 4);
  float* sArr = (float*)alloc(N_NODES * 4);
  unsigned short* Bt = (unsigned short*)alloc((size_t)NT * 128 * 256 * 2);
  unsigned short* X0 = (unsigned short*)alloc((size_t)N_NODES * IN_F * 2);
  unsigned short* G = (unsigned short*)alloc((size_t)N_NODES * 768 * 2);

  hipMemsetAsync(deg, 0, N_NODES * 4, stream);
  k_deg<<<(N_EDGES + 255) / 256, 256, 0, stream>>>(row, deg);
  k_scan1<<<79, 256, 0, stream>>>(deg, startofs, bsums, dinv);
  k_scan2<<<1, 128, 0, stream>>>(bsums, 79);
  k_scan3<<<79, 256, 0, stream>>>(startofs, cursor, bsums);
  k_scatter<<<(N_EDGES + 255) / 256, 256, 0, stream>>>(row, col, dinv, cursor, csr_col, csr_w);
  k_buildB<<<(NT * 128 * 256) / 256, 256, 0, stream>>>(W, means, lvar, Bt);
  k_prepx<<<N_NODES / 4, 256, 0, stream>>>(x, logp, means, lvar, X0, gamma);
  k_spmm<<<N_NODES, 64, 0, stream>>>(X0, startofs, deg, dinv, csr_col, csr_w, G, sArr);
  k_gemm_ep<<<dim3((N_NODES + 63) / 64, 2), 256, 0, stream>>>(G, Bt, gamma, sArr, bias, out);
}